// Round 4
// baseline (1151.517 us; speedup 1.0000x reference)
//
#include <hip/hip_runtime.h>

#define B_  2
#define NX_ 512
#define NC_ 4096
#define D_  1024
#define H_  16
#define HD_ 64
#define NT_ (NX_ + NC_)   // 4608

// ---------------- LayerNorm: x (B,NX,D) fp32 -> xn fp32 ----------------
__global__ __launch_bounds__(256)
void ln_kernel(const float* __restrict__ x,
               const float* __restrict__ lw,
               const float* __restrict__ lb,
               float* __restrict__ xn) {
    int row = blockIdx.x;          // 0 .. B*NX-1
    int tid = threadIdx.x;         // 256 threads, 4 elems each
    float4 v = reinterpret_cast<const float4*>(x)[(size_t)row * (D_ / 4) + tid];
    float s  = v.x + v.y + v.z + v.w;
    float s2 = v.x * v.x + v.y * v.y + v.z * v.z + v.w * v.w;
    #pragma unroll
    for (int off = 32; off > 0; off >>= 1) {
        s  += __shfl_down(s, off);
        s2 += __shfl_down(s2, off);
    }
    __shared__ float sm[4], sm2[4], stat[2];
    int wv = tid >> 6;
    if ((tid & 63) == 0) { sm[wv] = s; sm2[wv] = s2; }
    __syncthreads();
    if (tid == 0) {
        float S  = sm[0] + sm[1] + sm[2] + sm[3];
        float S2 = sm2[0] + sm2[1] + sm2[2] + sm2[3];
        float mu  = S * (1.0f / D_);
        float var = S2 * (1.0f / D_) - mu * mu;
        var = fmaxf(var, 0.0f);
        stat[0] = mu;
        stat[1] = rsqrtf(var + 1e-5f);
    }
    __syncthreads();
    float mu = stat[0], rs = stat[1];
    float4 w4 = reinterpret_cast<const float4*>(lw)[tid];
    float4 b4 = reinterpret_cast<const float4*>(lb)[tid];
    float4 o;
    o.x = (v.x - mu) * rs * w4.x + b4.x;
    o.y = (v.y - mu) * rs * w4.y + b4.y;
    o.z = (v.z - mu) * rs * w4.z + b4.z;
    o.w = (v.w - mu) * rs * w4.w + b4.w;
    reinterpret_cast<float4*>(xn)[(size_t)row * (D_ / 4) + tid] = o;
}

// ---------------- GEMM: C(MxN) = A(MxK) * B(KxN), all fp32 ----------------
#define BM 64
#define BN 64
#define BK 16
__global__ __launch_bounds__(256)
void gemm_kernel(const float* __restrict__ A, const float* __restrict__ Bm,
                 float* __restrict__ C, int M, int N, int K) {
    __shared__ float As[BK][BM + 1];
    __shared__ float Bs[BK][BN + 1];
    int tid = threadIdx.x;
    int tx = tid & 15, ty = tid >> 4;
    int row0 = blockIdx.y * BM, col0 = blockIdx.x * BN;
    float acc[4][4] = {};
    for (int k0 = 0; k0 < K; k0 += BK) {
        int am = tid >> 2, ak = (tid & 3) << 2;
        float4 av = *reinterpret_cast<const float4*>(A + (size_t)(row0 + am) * K + k0 + ak);
        As[ak + 0][am] = av.x; As[ak + 1][am] = av.y;
        As[ak + 2][am] = av.z; As[ak + 3][am] = av.w;
        int bk = tid >> 4, bn = (tid & 15) << 2;
        float4 bv = *reinterpret_cast<const float4*>(Bm + (size_t)(k0 + bk) * N + col0 + bn);
        Bs[bk][bn + 0] = bv.x; Bs[bk][bn + 1] = bv.y;
        Bs[bk][bn + 2] = bv.z; Bs[bk][bn + 3] = bv.w;
        __syncthreads();
        #pragma unroll
        for (int kk = 0; kk < BK; ++kk) {
            float ar[4], br[4];
            #pragma unroll
            for (int i = 0; i < 4; ++i) ar[i] = As[kk][ty * 4 + i];
            #pragma unroll
            for (int j = 0; j < 4; ++j) br[j] = Bs[kk][tx * 4 + j];
            #pragma unroll
            for (int i = 0; i < 4; ++i)
                #pragma unroll
                for (int j = 0; j < 4; ++j)
                    acc[i][j] += ar[i] * br[j];
        }
        __syncthreads();
    }
    #pragma unroll
    for (int i = 0; i < 4; ++i)
        #pragma unroll
        for (int j = 0; j < 4; ++j)
            C[(size_t)(row0 + ty * 4 + i) * N + col0 + tx * 4 + j] = acc[i][j];
}

// ---------------- kv0: out2[b,h,n,d] = c[b,n,h*64+d] (fp32 copy) ----------------
// NOTE: runs LAST — the out2 region doubles as fp32 scratch earlier in the launch.
__global__ __launch_bounds__(256)
void kv0_kernel(const float* __restrict__ c, float* __restrict__ out2) {
    size_t i = (size_t)blockIdx.x * 256 + threadIdx.x;   // one thread per 4 elems
    int d4 = (int)(i & 15);                              // HD/4 = 16
    size_t r = i >> 4;
    int n = (int)(r % NC_);
    size_t r2 = r / NC_;
    int h = (int)(r2 & (H_ - 1));
    int b = (int)(r2 >> 4);
    float4 v = *reinterpret_cast<const float4*>(c + ((size_t)(b * NC_ + n)) * D_ + h * HD_ + d4 * 4);
    reinterpret_cast<float4*>(out2)[i] = v;
}

// ---------------- Attention ----------------
// grid: 256 blocks = (b:2, h:16, qtile:8); block: 512 threads = 8 waves.
// Each thread owns one query; waves split the 4608 keys; LDS combine.
// Fixed-reference softmax: p = exp(min(s,64)-64) in (0,1], masked -> 0.
// Self-key score q.q/8 >= 0 guarantees l >= exp(-64) (normal fp32).
#define QT_ 64
#define AW_ 8
#define M0_ 64.0f
__global__ __launch_bounds__(512, 1)
void attn_kernel(const float* __restrict__ qbuf, const float* __restrict__ c,
                 const int* __restrict__ mask, float* __restrict__ abuf) {
    int blk = blockIdx.x;
    int qt = blk & 7;
    int h  = (blk >> 3) & 15;
    int b  = blk >> 7;
    int lane = threadIdx.x & 63;
    int wave = threadIdx.x >> 6;
    int q = qt * QT_ + lane;

    float qr[HD_], o[HD_];
    const float4* qp = reinterpret_cast<const float4*>(qbuf + ((size_t)(b * NX_) + q) * D_ + h * HD_);
    #pragma unroll
    for (int t = 0; t < 16; ++t) {
        float4 v = qp[t];
        qr[t * 4 + 0] = v.x * 0.125f; qr[t * 4 + 1] = v.y * 0.125f;
        qr[t * 4 + 2] = v.z * 0.125f; qr[t * 4 + 3] = v.w * 0.125f;
    }
    #pragma unroll
    for (int d = 0; d < HD_; ++d) o[d] = 0.0f;
    float l = 0.0f;

    const int per = NT_ / AW_;   // 576 keys per wave
    int j0 = wave * per, j1 = j0 + per;

    // region 1: appended-q keys (fp32 in qbuf), never masked
    int e1 = (j1 < NX_) ? j1 : NX_;
    const float* kqb = qbuf + (size_t)(b * NX_) * D_ + h * HD_;
    for (int j = j0; j < e1; ++j) {
        const float4* kp = reinterpret_cast<const float4*>(kqb + (size_t)j * D_);
        float kf[HD_];
        #pragma unroll
        for (int t = 0; t < 16; ++t) {
            float4 v = kp[t];
            kf[t * 4 + 0] = v.x; kf[t * 4 + 1] = v.y;
            kf[t * 4 + 2] = v.z; kf[t * 4 + 3] = v.w;
        }
        float sa = 0.f, sb = 0.f, sc = 0.f, sd = 0.f;
        #pragma unroll
        for (int t = 0; t < 16; ++t) {
            sa += qr[t * 4 + 0] * kf[t * 4 + 0];
            sb += qr[t * 4 + 1] * kf[t * 4 + 1];
            sc += qr[t * 4 + 2] * kf[t * 4 + 2];
            sd += qr[t * 4 + 3] * kf[t * 4 + 3];
        }
        float s = (sa + sb) + (sc + sd);
        float p = __expf(fminf(s, M0_) - M0_);
        l += p;
        #pragma unroll
        for (int d = 0; d < HD_; ++d) o[d] += p * kf[d];
    }

    // region 2: context keys (fp32 in c), masked per (b,q,jc)
    int s2i = (j0 > NX_) ? j0 : NX_;
    const float* kcb = c + (size_t)(b * NC_) * D_ + h * HD_;
    const int* mrow = mask + ((size_t)(b * NX_) + q) * NC_;
    for (int j = s2i; j < j1; ++j) {
        int jc = j - NX_;
        const float4* kp = reinterpret_cast<const float4*>(kcb + (size_t)jc * D_);
        float kf[HD_];
        #pragma unroll
        for (int t = 0; t < 16; ++t) {
            float4 v = kp[t];
            kf[t * 4 + 0] = v.x; kf[t * 4 + 1] = v.y;
            kf[t * 4 + 2] = v.z; kf[t * 4 + 3] = v.w;
        }
        int mk = mrow[jc];
        float sa = 0.f, sb = 0.f, sc = 0.f, sd = 0.f;
        #pragma unroll
        for (int t = 0; t < 16; ++t) {
            sa += qr[t * 4 + 0] * kf[t * 4 + 0];
            sb += qr[t * 4 + 1] * kf[t * 4 + 1];
            sc += qr[t * 4 + 2] * kf[t * 4 + 2];
            sd += qr[t * 4 + 3] * kf[t * 4 + 3];
        }
        float s = (sa + sb) + (sc + sd);
        float p = (mk != 0) ? __expf(fminf(s, M0_) - M0_) : 0.0f;
        l += p;
        #pragma unroll
        for (int d = 0; d < HD_; ++d) o[d] += p * kf[d];
    }

    // ---- combine the 8 per-wave partials in LDS (plain sums) ----
    __shared__ float red_l[AW_][QT_];
    __shared__ float o_acc[QT_][HD_ + 1];

    red_l[wave][lane] = l;
    __syncthreads();
    for (int w = 0; w < AW_; ++w) {
        if (wave == w) {
            if (w == 0) {
                #pragma unroll
                for (int d = 0; d < HD_; ++d) o_acc[lane][d] = o[d];
            } else {
                #pragma unroll
                for (int d = 0; d < HD_; ++d) o_acc[lane][d] += o[d];
            }
        }
        __syncthreads();
    }
    // write a[b, q, h*64+d] fp32
    float* ab = abuf + ((size_t)(b * NX_) + qt * QT_) * D_ + h * HD_;
    for (int i = threadIdx.x; i < QT_ * HD_; i += 512) {
        int ql = i >> 6, d = i & 63;
        float ltq = red_l[0][ql];
        #pragma unroll
        for (int w = 1; w < AW_; ++w) ltq += red_l[w][ql];
        ltq = fmaxf(ltq, 1e-30f);
        ab[(size_t)ql * D_ + d] = o_acc[ql][d] / ltq;
    }
}

extern "C" void kernel_launch(void* const* d_in, const int* in_sizes, int n_in,
                              void* d_out, int out_size, void* d_ws, size_t ws_size,
                              hipStream_t stream) {
    (void)in_sizes; (void)n_in; (void)out_size; (void)d_ws; (void)ws_size;
    const float* x    = (const float*)d_in[0];
    const float* c    = (const float*)d_in[1];
    const int*   mask = (const int*)d_in[2];
    const float* ln_w = (const float*)d_in[3];
    const float* ln_b = (const float*)d_in[4];
    const float* Wq   = (const float*)d_in[5];
    const float* Wo   = (const float*)d_in[6];
    float* out  = (float*)d_out;                    // o: B*NX*D = 1048576 floats
    float* out2 = out + (size_t)B_ * NX_ * D_;      // kv0: 8388608 floats (32 MB)

    // fp32 scratch lives inside the out2 region (32 MB >= 12 MB needed);
    // kv0_kernel runs LAST and overwrites it with the real kv0 output.
    float* xn   = out2;                           // 4 MB
    float* qbuf = xn   + (size_t)B_ * NX_ * D_;   // 4 MB
    float* abuf = qbuf + (size_t)B_ * NX_ * D_;   // 4 MB

    const int M = B_ * NX_;   // 1024

    ln_kernel<<<M, 256, 0, stream>>>(x, ln_w, ln_b, xn);
    gemm_kernel<<<dim3(D_ / BN, M / BM), 256, 0, stream>>>(xn, Wq, qbuf, M, D_, D_);
    attn_kernel<<<B_ * H_ * (NX_ / QT_), 512, 0, stream>>>(qbuf, c, mask, abuf);
    gemm_kernel<<<dim3(D_ / BN, M / BM), 256, 0, stream>>>(abuf, Wo, out, M, D_, D_);
    kv0_kernel<<<(B_ * H_ * NC_ * HD_ / 4) / 256, 256, 0, stream>>>(c, out2);
}

// Round 5
// 409.767 us; speedup vs baseline: 2.8102x; 2.8102x over previous
//
#include <hip/hip_runtime.h>

#define B_  2
#define NX_ 512
#define NC_ 4096
#define D_  1024
#define H_  16
#define HD_ 64
#define NT_ (NX_ + NC_)   // 4608

typedef float  floatx4  __attribute__((ext_vector_type(4)));
typedef __bf16 bf16x8   __attribute__((ext_vector_type(8)));
typedef unsigned short ushort8v __attribute__((ext_vector_type(8)));

__device__ __forceinline__ bf16x8 as_bf16x8(ushort8v u) {
    union { ushort8v u; bf16x8 b; } c; c.u = u; return c.b;
}
// fp32 -> bf16 with round-to-nearest-even
__device__ __forceinline__ unsigned short f2bf(float f) {
    unsigned u = __float_as_uint(f);
    u += 0x7FFF + ((u >> 16) & 1);
    return (unsigned short)(u >> 16);
}

// ---------------- LayerNorm: x (B,NX,D) fp32 -> xn fp32 ----------------
__global__ __launch_bounds__(256)
void ln_kernel(const float* __restrict__ x,
               const float* __restrict__ lw,
               const float* __restrict__ lb,
               float* __restrict__ xn) {
    int row = blockIdx.x;
    int tid = threadIdx.x;
    float4 v = reinterpret_cast<const float4*>(x)[(size_t)row * (D_ / 4) + tid];
    float s  = v.x + v.y + v.z + v.w;
    float s2 = v.x * v.x + v.y * v.y + v.z * v.z + v.w * v.w;
    #pragma unroll
    for (int off = 32; off > 0; off >>= 1) {
        s  += __shfl_down(s, off);
        s2 += __shfl_down(s2, off);
    }
    __shared__ float sm[4], sm2[4], stat[2];
    int wv = tid >> 6;
    if ((tid & 63) == 0) { sm[wv] = s; sm2[wv] = s2; }
    __syncthreads();
    if (tid == 0) {
        float S  = sm[0] + sm[1] + sm[2] + sm[3];
        float S2 = sm2[0] + sm2[1] + sm2[2] + sm2[3];
        float mu  = S * (1.0f / D_);
        float var = fmaxf(S2 * (1.0f / D_) - mu * mu, 0.0f);
        stat[0] = mu;
        stat[1] = rsqrtf(var + 1e-5f);
    }
    __syncthreads();
    float mu = stat[0], rs = stat[1];
    float4 w4 = reinterpret_cast<const float4*>(lw)[tid];
    float4 b4 = reinterpret_cast<const float4*>(lb)[tid];
    float4 o;
    o.x = (v.x - mu) * rs * w4.x + b4.x;
    o.y = (v.y - mu) * rs * w4.y + b4.y;
    o.z = (v.z - mu) * rs * w4.z + b4.z;
    o.w = (v.w - mu) * rs * w4.w + b4.w;
    reinterpret_cast<float4*>(xn)[(size_t)row * (D_ / 4) + tid] = o;
}

// ---------------- GEMM: C(MxN) = A(MxK) * B(KxN) fp32; out fp32 or bf16 ----------------
#define BM 64
#define BN 64
#define BK 16
__global__ __launch_bounds__(256)
void gemm_kernel(const float* __restrict__ A, const float* __restrict__ Bm,
                 float* __restrict__ Cf, unsigned short* __restrict__ Cb,
                 int M, int N, int K) {
    __shared__ float As[BK][BM + 1];
    __shared__ float Bs[BK][BN + 1];
    int tid = threadIdx.x;
    int tx = tid & 15, ty = tid >> 4;
    int row0 = blockIdx.y * BM, col0 = blockIdx.x * BN;
    float acc[4][4] = {};
    for (int k0 = 0; k0 < K; k0 += BK) {
        int am = tid >> 2, ak = (tid & 3) << 2;
        float4 av = *reinterpret_cast<const float4*>(A + (size_t)(row0 + am) * K + k0 + ak);
        As[ak + 0][am] = av.x; As[ak + 1][am] = av.y;
        As[ak + 2][am] = av.z; As[ak + 3][am] = av.w;
        int bk = tid >> 4, bn = (tid & 15) << 2;
        float4 bv = *reinterpret_cast<const float4*>(Bm + (size_t)(k0 + bk) * N + col0 + bn);
        Bs[bk][bn + 0] = bv.x; Bs[bk][bn + 1] = bv.y;
        Bs[bk][bn + 2] = bv.z; Bs[bk][bn + 3] = bv.w;
        __syncthreads();
        #pragma unroll
        for (int kk = 0; kk < BK; ++kk) {
            float ar[4], br[4];
            #pragma unroll
            for (int i = 0; i < 4; ++i) ar[i] = As[kk][ty * 4 + i];
            #pragma unroll
            for (int j = 0; j < 4; ++j) br[j] = Bs[kk][tx * 4 + j];
            #pragma unroll
            for (int i = 0; i < 4; ++i)
                #pragma unroll
                for (int j = 0; j < 4; ++j)
                    acc[i][j] += ar[i] * br[j];
        }
        __syncthreads();
    }
    #pragma unroll
    for (int i = 0; i < 4; ++i) {
        #pragma unroll
        for (int j = 0; j < 4; ++j) {
            size_t idx = (size_t)(row0 + ty * 4 + i) * N + col0 + tx * 4 + j;
            if (Cb) Cb[idx] = f2bf(acc[i][j]);
            else    Cf[idx] = acc[i][j];
        }
    }
}

// ---------------- cast fp32 -> bf16 (4 elems/thread) ----------------
__global__ __launch_bounds__(256)
void cast_bf16_kernel(const float* __restrict__ in, unsigned short* __restrict__ outp) {
    size_t i = ((size_t)blockIdx.x * 256 + threadIdx.x) * 4;
    float4 v = *reinterpret_cast<const float4*>(in + i);
    ushort4 o;
    o.x = f2bf(v.x); o.y = f2bf(v.y); o.z = f2bf(v.z); o.w = f2bf(v.w);
    *reinterpret_cast<ushort4*>(outp + i) = o;
}

// ---------------- mask (int 0/1) -> bitmask, 1 word (32 keys) per thread ----------------
__global__ __launch_bounds__(256)
void pack_mask_kernel(const int* __restrict__ mask, unsigned* __restrict__ bits) {
    size_t w = (size_t)blockIdx.x * 256 + threadIdx.x;   // 131072 words total
    const int* src = mask + w * 32;
    unsigned b = 0;
    #pragma unroll
    for (int c = 0; c < 8; ++c) {
        int4 v = reinterpret_cast<const int4*>(src)[c];
        b |= (v.x != 0 ? 1u : 0u) << (c * 4 + 0);
        b |= (v.y != 0 ? 1u : 0u) << (c * 4 + 1);
        b |= (v.z != 0 ? 1u : 0u) << (c * 4 + 2);
        b |= (v.w != 0 ? 1u : 0u) << (c * 4 + 3);
    }
    bits[w] = b;
}

// ---------------- kv0: out2[b,h,n,d] = c[b,n,h*64+d] (fp32 copy) — runs LAST ----------------
__global__ __launch_bounds__(256)
void kv0_kernel(const float* __restrict__ c, float* __restrict__ out2) {
    size_t i = (size_t)blockIdx.x * 256 + threadIdx.x;
    int d4 = (int)(i & 15);
    size_t r = i >> 4;
    int n = (int)(r % NC_);
    size_t r2 = r / NC_;
    int h = (int)(r2 & (H_ - 1));
    int b = (int)(r2 >> 4);
    float4 v = *reinterpret_cast<const float4*>(c + ((size_t)(b * NC_ + n)) * D_ + h * HD_ + d4 * 4);
    reinterpret_cast<float4*>(out2)[i] = v;
}

// ---------------- MFMA flash attention ----------------
// 256 blocks = (b:2, h:16, qt:8); 256 threads = 4 waves; wave w owns q-rows [16w,16w+16).
// Fixed-reference softmax p = exp(s-64): LINEAR -> no online rescale needed.
// Verified gfx950 16x16x32 layouts: A[m=lane&15][k=(lane>>4)*8+j];
// B[k=(lane>>4)*8+j][n=lane&15]; C/D row=(lane>>4)*4+reg, col=lane&15.
#define PADW 72   // 64 + 8 bf16 pad: frag-read rows land 2-way max (free, m136)
__global__ __launch_bounds__(256)
void attn_mfma_kernel(const unsigned short* __restrict__ qbf,
                      const unsigned short* __restrict__ cbf,
                      const unsigned* __restrict__ maskbits,
                      float* __restrict__ abuf) {
    int blk = blockIdx.x;
    int qt = blk & 7;
    int h  = (blk >> 3) & 15;
    int b  = blk >> 7;
    int tid  = threadIdx.x;
    int lane = tid & 63;
    int wave = tid >> 6;          // 0..3
    int m16  = lane & 15;
    int g    = lane >> 4;         // 0..3
    int g8   = g * 8;

    __shared__ unsigned short Qs [64][PADW];
    __shared__ unsigned short Ks [64][PADW];
    __shared__ unsigned short Kts[64][PADW];
    __shared__ unsigned short Ps [64][PADW];

    // ---- load Q tile (64 q-rows x 64 dims, bf16) ----
    {
        int r = tid >> 2, dch = (tid & 3) * 16;
        const unsigned short* qsrc = qbf + ((size_t)(b * NX_ + qt * 64 + r)) * D_ + h * HD_ + dch;
        uint4 u0 = *reinterpret_cast<const uint4*>(qsrc);
        uint4 u1 = *reinterpret_cast<const uint4*>(qsrc + 8);
        *reinterpret_cast<uint4*>(&Qs[r][dch])     = u0;
        *reinterpret_cast<uint4*>(&Qs[r][dch + 8]) = u1;
    }
    __syncthreads();

    // A-frags of Q are invariant across key-blocks — load once
    bf16x8 qa0 = as_bf16x8(*reinterpret_cast<ushort8v*>(&Qs[16 * wave + m16][g8]));
    bf16x8 qa1 = as_bf16x8(*reinterpret_cast<ushort8v*>(&Qs[16 * wave + m16][32 + g8]));

    floatx4 acc_o[4];
    #pragma unroll
    for (int td = 0; td < 4; ++td) acc_o[td] = (floatx4){0.f, 0.f, 0.f, 0.f};
    float l_acc[4] = {0.f, 0.f, 0.f, 0.f};

    for (int kb = 0; kb < NT_ / 64; ++kb) {     // 72 key-blocks
        __syncthreads();                        // prior PV done with Ks/Kts
        // ---- stage K tile: Ks[key][d] and Kts[d][key] ----
        {
            int keyl = tid >> 2, dch = (tid & 3) * 16;
            const unsigned short* src;
            if (kb < 8)
                src = qbf + ((size_t)(b * NX_ + kb * 64 + keyl)) * D_ + h * HD_ + dch;
            else
                src = cbf + ((size_t)(b * NC_ + kb * 64 - NX_ + keyl)) * D_ + h * HD_ + dch;
            union { uint4 v[2]; unsigned short s[16]; } u;
            u.v[0] = *reinterpret_cast<const uint4*>(src);
            u.v[1] = *reinterpret_cast<const uint4*>(src + 8);
            *reinterpret_cast<uint4*>(&Ks[keyl][dch])     = u.v[0];
            *reinterpret_cast<uint4*>(&Ks[keyl][dch + 8]) = u.v[1];
            #pragma unroll
            for (int i = 0; i < 16; ++i) Kts[dch + i][keyl] = u.s[i];
        }
        __syncthreads();

        // ---- S = Q @ K^T (wave strip: 16 q-rows x 64 keys) ----
        floatx4 accs[4];
        #pragma unroll
        for (int t = 0; t < 4; ++t) {
            bf16x8 b0 = as_bf16x8(*reinterpret_cast<ushort8v*>(&Ks[16 * t + m16][g8]));
            bf16x8 b1 = as_bf16x8(*reinterpret_cast<ushort8v*>(&Ks[16 * t + m16][32 + g8]));
            floatx4 d = (floatx4){0.f, 0.f, 0.f, 0.f};
            d = __builtin_amdgcn_mfma_f32_16x16x32_bf16(qa0, b0, d, 0, 0, 0);
            d = __builtin_amdgcn_mfma_f32_16x16x32_bf16(qa1, b1, d, 0, 0, 0);
            accs[t] = d;
        }

        // ---- mask bits for this key-block (2 words cover 64 keys per q-row) ----
        unsigned mw0[4], mw1[4];
        if (kb >= 8) {
            #pragma unroll
            for (int r = 0; r < 4; ++r) {
                size_t mi = ((size_t)(b * NX_ + qt * 64 + 16 * wave + g * 4 + r)) * (NC_ / 32)
                          + (size_t)(kb - 8) * 2;
                uint2 w = *reinterpret_cast<const uint2*>(&maskbits[mi]);
                mw0[r] = w.x; mw1[r] = w.y;
            }
        }

        // ---- p = exp(s*scale - 64), masked -> 0; write P strip; row partial sums ----
        float psum[4] = {0.f, 0.f, 0.f, 0.f};
        #pragma unroll
        for (int t = 0; t < 4; ++t) {
            #pragma unroll
            for (int r = 0; r < 4; ++r) {
                float s = accs[t][r] * 0.125f;
                float p = __expf(fminf(s, 64.0f) - 64.0f);
                if (kb >= 8) {
                    unsigned w = (t < 2) ? mw0[r] : mw1[r];
                    unsigned bit = (w >> ((16 * t + m16) & 31)) & 1u;
                    p = bit ? p : 0.0f;
                }
                psum[r] += p;
                Ps[16 * wave + g * 4 + r][16 * t + m16] = f2bf(p);
            }
        }
        #pragma unroll
        for (int r = 0; r < 4; ++r) {
            float v = psum[r];
            v += __shfl_xor(v, 1, 16);
            v += __shfl_xor(v, 2, 16);
            v += __shfl_xor(v, 4, 16);
            v += __shfl_xor(v, 8, 16);
            l_acc[r] += v;
        }
        // own-wave LDS round-trip: drain ds_writes before cross-lane ds_reads
        asm volatile("s_waitcnt lgkmcnt(0)" ::: "memory");

        // ---- O += P @ V (V = K tile, read from Kts) ----
        bf16x8 p0 = as_bf16x8(*reinterpret_cast<ushort8v*>(&Ps[16 * wave + m16][g8]));
        bf16x8 p1 = as_bf16x8(*reinterpret_cast<ushort8v*>(&Ps[16 * wave + m16][32 + g8]));
        #pragma unroll
        for (int td = 0; td < 4; ++td) {
            bf16x8 v0 = as_bf16x8(*reinterpret_cast<ushort8v*>(&Kts[16 * td + m16][g8]));
            bf16x8 v1 = as_bf16x8(*reinterpret_cast<ushort8v*>(&Kts[16 * td + m16][32 + g8]));
            acc_o[td] = __builtin_amdgcn_mfma_f32_16x16x32_bf16(p0, v0, acc_o[td], 0, 0, 0);
            acc_o[td] = __builtin_amdgcn_mfma_f32_16x16x32_bf16(p1, v1, acc_o[td], 0, 0, 0);
        }
    }

    // ---- epilogue: normalize, write a[b, q, h*64+d] fp32 ----
    #pragma unroll
    for (int r = 0; r < 4; ++r) {
        float l = fmaxf(l_acc[r], 1e-30f);
        float inv = 1.0f / l;
        int qrow = qt * 64 + 16 * wave + g * 4 + r;
        float* dst = abuf + ((size_t)(b * NX_ + qrow)) * D_ + h * HD_;
        #pragma unroll
        for (int td = 0; td < 4; ++td)
            dst[16 * td + m16] = acc_o[td][r] * inv;
    }
}

extern "C" void kernel_launch(void* const* d_in, const int* in_sizes, int n_in,
                              void* d_out, int out_size, void* d_ws, size_t ws_size,
                              hipStream_t stream) {
    (void)in_sizes; (void)n_in; (void)out_size; (void)d_ws; (void)ws_size;
    const float* x    = (const float*)d_in[0];
    const float* c    = (const float*)d_in[1];
    const int*   mask = (const int*)d_in[2];
    const float* ln_w = (const float*)d_in[3];
    const float* ln_b = (const float*)d_in[4];
    const float* Wq   = (const float*)d_in[5];
    const float* Wo   = (const float*)d_in[6];
    float* out  = (float*)d_out;                    // o: 1,048,576 floats
    float* out2 = out + (size_t)B_ * NX_ * D_;      // kv0: 8,388,608 floats (32 MB)

    // scratch inside out2 region (kv0_kernel runs LAST and overwrites it):
    float*          base     = out2;
    float*          xn       = base;                                    // 4 MB fp32
    float*          abuf     = base;                                    // alias (xn dead after gemm1)
    unsigned short* qbf      = (unsigned short*)(base + 1048576);       // 2 MB bf16
    unsigned short* cbf      = (unsigned short*)(base + 1048576 + 524288); // 16 MB bf16
    unsigned*       maskbits = (unsigned*)(base + 1048576 + 524288 + 4194304); // 0.5 MB

    const int M = B_ * NX_;   // 1024

    ln_kernel<<<M, 256, 0, stream>>>(x, ln_w, ln_b, xn);
    cast_bf16_kernel<<<(B_ * NC_ * D_ / 4) / 256, 256, 0, stream>>>(c, cbf);
    pack_mask_kernel<<<(B_ * NX_ * NC_ / 32) / 256, 256, 0, stream>>>(mask, maskbits);
    gemm_kernel<<<dim3(D_ / BN, M / BM), 256, 0, stream>>>(xn, Wq, nullptr, qbf, M, D_, D_);
    attn_mfma_kernel<<<B_ * H_ * (NX_ / 64), 256, 0, stream>>>(qbf, cbf, maskbits, abuf);
    gemm_kernel<<<dim3(D_ / BN, M / BM), 256, 0, stream>>>(abuf, Wo, out, nullptr, M, D_, D_);
    kv0_kernel<<<(B_ * H_ * NC_ * HD_ / 4) / 256, 256, 0, stream>>>(c, out2);
}

// Round 6
// 227.681 us; speedup vs baseline: 5.0576x; 1.7997x over previous
//
#include <hip/hip_runtime.h>

#define B_  2
#define NX_ 512
#define NC_ 4096
#define D_  1024
#define H_  16
#define HD_ 64
#define NT_ (NX_ + NC_)   // 4608
#define NSPLIT 4
#define KBS (NT_ / 64 / NSPLIT)   // 18 key-blocks per split

typedef float  floatx4  __attribute__((ext_vector_type(4)));
typedef __bf16 bf16x8   __attribute__((ext_vector_type(8)));
typedef unsigned short ushort8v __attribute__((ext_vector_type(8)));

__device__ __forceinline__ bf16x8 as_bf16x8(ushort8v u) {
    union { ushort8v u; bf16x8 b; } c; c.u = u; return c.b;
}
// fp32 -> bf16 round-to-nearest-even
__device__ __forceinline__ unsigned short f2bf(float f) {
    unsigned u = __float_as_uint(f);
    u += 0x7FFF + ((u >> 16) & 1);
    return (unsigned short)(u >> 16);
}

// ---------------- LayerNorm: x fp32 -> xn bf16 ----------------
__global__ __launch_bounds__(256)
void ln_kernel(const float* __restrict__ x,
               const float* __restrict__ lw,
               const float* __restrict__ lb,
               unsigned short* __restrict__ xnb) {
    int row = blockIdx.x;
    int tid = threadIdx.x;
    float4 v = reinterpret_cast<const float4*>(x)[(size_t)row * (D_ / 4) + tid];
    float s  = v.x + v.y + v.z + v.w;
    float s2 = v.x * v.x + v.y * v.y + v.z * v.z + v.w * v.w;
    #pragma unroll
    for (int off = 32; off > 0; off >>= 1) {
        s  += __shfl_down(s, off);
        s2 += __shfl_down(s2, off);
    }
    __shared__ float sm[4], sm2[4], stat[2];
    int wv = tid >> 6;
    if ((tid & 63) == 0) { sm[wv] = s; sm2[wv] = s2; }
    __syncthreads();
    if (tid == 0) {
        float S  = sm[0] + sm[1] + sm[2] + sm[3];
        float S2 = sm2[0] + sm2[1] + sm2[2] + sm2[3];
        float mu  = S * (1.0f / D_);
        float var = fmaxf(S2 * (1.0f / D_) - mu * mu, 0.0f);
        stat[0] = mu;
        stat[1] = rsqrtf(var + 1e-5f);
    }
    __syncthreads();
    float mu = stat[0], rs = stat[1];
    float4 w4 = reinterpret_cast<const float4*>(lw)[tid];
    float4 b4 = reinterpret_cast<const float4*>(lb)[tid];
    ushort4 o;
    o.x = f2bf((v.x - mu) * rs * w4.x + b4.x);
    o.y = f2bf((v.y - mu) * rs * w4.y + b4.y);
    o.z = f2bf((v.z - mu) * rs * w4.z + b4.z);
    o.w = f2bf((v.w - mu) * rs * w4.w + b4.w);
    reinterpret_cast<ushort4*>(xnb)[(size_t)row * (D_ / 4) + tid] = o;
}

// ---------------- transpose+cast: W (KxN fp32) -> WT (NxK bf16), 64x64 tiles ----------------
__global__ __launch_bounds__(256)
void tcast_kernel(const float* __restrict__ W, unsigned short* __restrict__ WT) {
    __shared__ unsigned short T[64][72];
    int row0 = blockIdx.y * 64, col0 = blockIdx.x * 64;
    int tid = threadIdx.x;
    int r = tid >> 2, ch = (tid & 3) * 16;
    const float* src = W + (size_t)(row0 + r) * D_ + col0 + ch;
    unsigned short vals[16];
    #pragma unroll
    for (int t = 0; t < 4; ++t) {
        float4 v = reinterpret_cast<const float4*>(src)[t];
        vals[t*4+0] = f2bf(v.x); vals[t*4+1] = f2bf(v.y);
        vals[t*4+2] = f2bf(v.z); vals[t*4+3] = f2bf(v.w);
    }
    #pragma unroll
    for (int i = 0; i < 16; ++i) T[ch + i][r] = vals[i];   // transpose in LDS
    __syncthreads();
    unsigned short* dst = WT + (size_t)(col0 + r) * D_ + row0 + ch;
    uint4 o0 = *reinterpret_cast<uint4*>(&T[r][ch]);
    uint4 o1 = *reinterpret_cast<uint4*>(&T[r][ch + 8]);
    *reinterpret_cast<uint4*>(dst)     = o0;
    *reinterpret_cast<uint4*>(dst + 8) = o1;
}

// ---------------- mask (int 0/1) -> bitmask ----------------
__global__ __launch_bounds__(256)
void pack_mask_kernel(const int* __restrict__ mask, unsigned* __restrict__ bits) {
    size_t w = (size_t)blockIdx.x * 256 + threadIdx.x;
    const int* src = mask + w * 32;
    unsigned b = 0;
    #pragma unroll
    for (int c = 0; c < 8; ++c) {
        int4 v = reinterpret_cast<const int4*>(src)[c];
        b |= (v.x != 0 ? 1u : 0u) << (c * 4 + 0);
        b |= (v.y != 0 ? 1u : 0u) << (c * 4 + 1);
        b |= (v.z != 0 ? 1u : 0u) << (c * 4 + 2);
        b |= (v.w != 0 ? 1u : 0u) << (c * 4 + 3);
    }
    bits[w] = b;
}

// ---------------- kv0: out2[b,h,n,d] = c[b,n,h*64+d] (fp32) — runs LAST ----------------
__global__ __launch_bounds__(256)
void kv0_kernel(const float* __restrict__ c, float* __restrict__ out2) {
    size_t i = (size_t)blockIdx.x * 256 + threadIdx.x;
    int d4 = (int)(i & 15);
    size_t r = i >> 4;
    int n = (int)(r % NC_);
    size_t r2 = r / NC_;
    int h = (int)(r2 & (H_ - 1));
    int b = (int)(r2 >> 4);
    float4 v = *reinterpret_cast<const float4*>(c + ((size_t)(b * NC_ + n)) * D_ + h * HD_ + d4 * 4);
    reinterpret_cast<float4*>(out2)[i] = v;
}

// ---------------- MFMA GEMM: C(1024x1024) = A(bf16 MxK) @ B, B given as BT(NxK bf16) ----------------
// 256 blocks (16x16), 256 threads / 4 waves; wave strip = 16 rows; out fp32 or bf16.
__global__ __launch_bounds__(256)
void gemm_bt_kernel(const unsigned short* __restrict__ A, const unsigned short* __restrict__ BT,
                    float* __restrict__ Cf, unsigned short* __restrict__ Cb) {
    __shared__ unsigned short As[64][72];
    __shared__ unsigned short Bs[64][72];
    int tid = threadIdx.x;
    int lane = tid & 63, wave = tid >> 6;
    int m16 = lane & 15, g = lane >> 4, g8 = g * 8;
    int row0 = blockIdx.y * 64, col0 = blockIdx.x * 64;
    int r = tid >> 2, ch = (tid & 3) * 16;

    floatx4 acc[4];
    #pragma unroll
    for (int t = 0; t < 4; ++t) acc[t] = (floatx4){0.f, 0.f, 0.f, 0.f};

    for (int kc = 0; kc < 16; ++kc) {
        int k0 = kc * 64;
        const unsigned short* asrc = A  + (size_t)(row0 + r) * D_ + k0 + ch;
        const unsigned short* bsrc = BT + (size_t)(col0 + r) * D_ + k0 + ch;
        uint4 a0 = *reinterpret_cast<const uint4*>(asrc);
        uint4 a1 = *reinterpret_cast<const uint4*>(asrc + 8);
        uint4 b0 = *reinterpret_cast<const uint4*>(bsrc);
        uint4 b1 = *reinterpret_cast<const uint4*>(bsrc + 8);
        *reinterpret_cast<uint4*>(&As[r][ch])     = a0;
        *reinterpret_cast<uint4*>(&As[r][ch + 8]) = a1;
        *reinterpret_cast<uint4*>(&Bs[r][ch])     = b0;
        *reinterpret_cast<uint4*>(&Bs[r][ch + 8]) = b1;
        __syncthreads();
        bf16x8 fa0 = as_bf16x8(*reinterpret_cast<ushort8v*>(&As[16 * wave + m16][g8]));
        bf16x8 fa1 = as_bf16x8(*reinterpret_cast<ushort8v*>(&As[16 * wave + m16][32 + g8]));
        #pragma unroll
        for (int t = 0; t < 4; ++t) {
            bf16x8 fb0 = as_bf16x8(*reinterpret_cast<ushort8v*>(&Bs[16 * t + m16][g8]));
            bf16x8 fb1 = as_bf16x8(*reinterpret_cast<ushort8v*>(&Bs[16 * t + m16][32 + g8]));
            acc[t] = __builtin_amdgcn_mfma_f32_16x16x32_bf16(fa0, fb0, acc[t], 0, 0, 0);
            acc[t] = __builtin_amdgcn_mfma_f32_16x16x32_bf16(fa1, fb1, acc[t], 0, 0, 0);
        }
        __syncthreads();
    }
    #pragma unroll
    for (int t = 0; t < 4; ++t) {
        #pragma unroll
        for (int reg = 0; reg < 4; ++reg) {
            size_t idx = (size_t)(row0 + 16 * wave + g * 4 + reg) * D_ + col0 + 16 * t + m16;
            if (Cb) Cb[idx] = f2bf(acc[t][reg]);
            else    Cf[idx] = acc[t][reg];
        }
    }
}

// ---------------- MFMA flash attention, split-K x4 ----------------
// grid 1024 = (split:4, b:2, h:16, qt:8); 256 thr / 4 waves; wave owns 16 q-rows.
// Linear fixed-ref softmax p=exp(s/8-64): partials over key subsets just add.
// Kts uses XOR-swizzled pad-free layout: phys chunk = key_chunk ^ ((d>>3)&7)
//   -> transpose writes hit 32 distinct banks (conflict-free), PV reads stay b128.
__global__ __launch_bounds__(256, 4)
void attn_kernel(const unsigned short* __restrict__ qbf,
                 const float* __restrict__ c,
                 const unsigned* __restrict__ maskbits,
                 float* __restrict__ part_o, float* __restrict__ part_l) {
    int blk   = blockIdx.x;
    int split = blk >> 8;
    int rblk  = blk & 255;
    int qt = rblk & 7;
    int h  = (rblk >> 3) & 15;
    int b  = rblk >> 7;
    int tid  = threadIdx.x;
    int lane = tid & 63;
    int wave = tid >> 6;
    int m16  = lane & 15;
    int g    = lane >> 4;
    int g8   = g * 8;

    __shared__ unsigned short Ks [64][72];
    __shared__ unsigned short Kts[64][64];
    __shared__ unsigned short Ps [64][72];

    // Q A-frags direct from global (once)
    const unsigned short* qrow = qbf + ((size_t)(b * NX_ + qt * 64 + 16 * wave + m16)) * D_ + h * HD_;
    bf16x8 qa0 = as_bf16x8(*reinterpret_cast<const ushort8v*>(qrow + g8));
    bf16x8 qa1 = as_bf16x8(*reinterpret_cast<const ushort8v*>(qrow + 32 + g8));

    floatx4 acc_o[4];
    #pragma unroll
    for (int td = 0; td < 4; ++td) acc_o[td] = (floatx4){0.f, 0.f, 0.f, 0.f};
    float l_acc[4] = {0.f, 0.f, 0.f, 0.f};

    int keyl = tid >> 2, dch = (tid & 3) * 16;

    for (int i = 0; i < KBS; ++i) {
        int kb = split * KBS + i;
        __syncthreads();                       // prior PV done with Ks/Kts
        // ---- stage K tile (bf16) into Ks rows + swizzled Kts ----
        unsigned short vals[16];
        if (kb < 8) {
            const unsigned short* src = qbf + ((size_t)(b * NX_ + kb * 64 + keyl)) * D_ + h * HD_ + dch;
            union { uint4 v[2]; unsigned short s[16]; } u;
            u.v[0] = *reinterpret_cast<const uint4*>(src);
            u.v[1] = *reinterpret_cast<const uint4*>(src + 8);
            #pragma unroll
            for (int k = 0; k < 16; ++k) vals[k] = u.s[k];
        } else {
            const float* src = c + ((size_t)(b * NC_ + kb * 64 - NX_ + keyl)) * D_ + h * HD_ + dch;
            #pragma unroll
            for (int t = 0; t < 4; ++t) {
                float4 v = reinterpret_cast<const float4*>(src)[t];
                vals[t*4+0] = f2bf(v.x); vals[t*4+1] = f2bf(v.y);
                vals[t*4+2] = f2bf(v.z); vals[t*4+3] = f2bf(v.w);
            }
        }
        *reinterpret_cast<uint4*>(&Ks[keyl][dch])     = *reinterpret_cast<uint4*>(&vals[0]);
        *reinterpret_cast<uint4*>(&Ks[keyl][dch + 8]) = *reinterpret_cast<uint4*>(&vals[8]);
        #pragma unroll
        for (int k = 0; k < 16; ++k) {
            int d = dch + k;
            int s = (d >> 3) & 7;
            int pc = ((((keyl >> 3) ^ s) << 3) | (keyl & 7));
            Kts[d][pc] = vals[k];
        }
        __syncthreads();

        // ---- S = Q @ K^T ----
        floatx4 accs[4];
        #pragma unroll
        for (int t = 0; t < 4; ++t) {
            bf16x8 b0 = as_bf16x8(*reinterpret_cast<ushort8v*>(&Ks[16 * t + m16][g8]));
            bf16x8 b1 = as_bf16x8(*reinterpret_cast<ushort8v*>(&Ks[16 * t + m16][32 + g8]));
            floatx4 d = (floatx4){0.f, 0.f, 0.f, 0.f};
            d = __builtin_amdgcn_mfma_f32_16x16x32_bf16(qa0, b0, d, 0, 0, 0);
            d = __builtin_amdgcn_mfma_f32_16x16x32_bf16(qa1, b1, d, 0, 0, 0);
            accs[t] = d;
        }

        unsigned mw0[4], mw1[4];
        if (kb >= 8) {
            #pragma unroll
            for (int r = 0; r < 4; ++r) {
                size_t mi = ((size_t)(b * NX_ + qt * 64 + 16 * wave + g * 4 + r)) * (NC_ / 32)
                          + (size_t)(kb - 8) * 2;
                uint2 w = *reinterpret_cast<const uint2*>(&maskbits[mi]);
                mw0[r] = w.x; mw1[r] = w.y;
            }
        }

        // ---- p = exp(s/8 - 64), masked -> 0; P strip; row partial sums ----
        float psum[4] = {0.f, 0.f, 0.f, 0.f};
        #pragma unroll
        for (int t = 0; t < 4; ++t) {
            #pragma unroll
            for (int r = 0; r < 4; ++r) {
                float s = accs[t][r] * 0.125f;
                float p = __expf(fminf(s, 64.0f) - 64.0f);
                if (kb >= 8) {
                    unsigned w = (t < 2) ? mw0[r] : mw1[r];
                    unsigned bit = (w >> ((16 * t + m16) & 31)) & 1u;
                    p = bit ? p : 0.0f;
                }
                psum[r] += p;
                Ps[16 * wave + g * 4 + r][16 * t + m16] = f2bf(p);
            }
        }
        #pragma unroll
        for (int r = 0; r < 4; ++r) {
            float v = psum[r];
            v += __shfl_xor(v, 1, 16);
            v += __shfl_xor(v, 2, 16);
            v += __shfl_xor(v, 4, 16);
            v += __shfl_xor(v, 8, 16);
            l_acc[r] += v;
        }
        asm volatile("s_waitcnt lgkmcnt(0)" ::: "memory");   // own-strip Ps round-trip

        // ---- O += P @ V (V rows from swizzled Kts) ----
        bf16x8 p0 = as_bf16x8(*reinterpret_cast<ushort8v*>(&Ps[16 * wave + m16][g8]));
        bf16x8 p1 = as_bf16x8(*reinterpret_cast<ushort8v*>(&Ps[16 * wave + m16][32 + g8]));
        #pragma unroll
        for (int td = 0; td < 4; ++td) {
            int row = 16 * td + m16;
            int s = (row >> 3) & 7;
            bf16x8 v0 = as_bf16x8(*reinterpret_cast<ushort8v*>(&Kts[row][(g ^ s) << 3]));
            bf16x8 v1 = as_bf16x8(*reinterpret_cast<ushort8v*>(&Kts[row][((4 + g) ^ s) << 3]));
            acc_o[td] = __builtin_amdgcn_mfma_f32_16x16x32_bf16(p0, v0, acc_o[td], 0, 0, 0);
            acc_o[td] = __builtin_amdgcn_mfma_f32_16x16x32_bf16(p1, v1, acc_o[td], 0, 0, 0);
        }
    }

    // ---- epilogue: write UNNORMALIZED partial O + partial l ----
    #pragma unroll
    for (int r = 0; r < 4; ++r) {
        int qrow_ = qt * 64 + 16 * wave + g * 4 + r;
        float* dst = part_o + (size_t)split * (B_ * NX_ * D_)
                   + ((size_t)(b * NX_ + qrow_)) * D_ + h * HD_;
        #pragma unroll
        for (int td = 0; td < 4; ++td)
            dst[16 * td + m16] = acc_o[td][r];
        if (m16 == 0)
            part_l[(size_t)split * (B_ * NX_ * H_) + (size_t)(b * NX_ + qrow_) * H_ + h] = l_acc[r];
    }
}

// ---------------- combine: sum 4 split partials, normalize, write bf16 ----------------
__global__ __launch_bounds__(256)
void combine_kernel(const float* __restrict__ part_o, const float* __restrict__ part_l,
                    unsigned short* __restrict__ abuf) {
    size_t gtid = (size_t)blockIdx.x * 256 + threadIdx.x;
    size_t idx4 = gtid * 4;                       // element index into (B*NX, D)
    size_t bq = idx4 >> 10;
    int h = (int)((idx4 & 1023) >> 6);
    float4 sum = {0.f, 0.f, 0.f, 0.f};
    float lsum = 0.f;
    #pragma unroll
    for (int s = 0; s < NSPLIT; ++s) {
        float4 v = *reinterpret_cast<const float4*>(part_o + (size_t)s * (B_ * NX_ * D_) + idx4);
        sum.x += v.x; sum.y += v.y; sum.z += v.z; sum.w += v.w;
        lsum += part_l[(size_t)s * (B_ * NX_ * H_) + bq * H_ + h];
    }
    float inv = 1.0f / fmaxf(lsum, 1e-30f);
    ushort4 o;
    o.x = f2bf(sum.x * inv); o.y = f2bf(sum.y * inv);
    o.z = f2bf(sum.z * inv); o.w = f2bf(sum.w * inv);
    *reinterpret_cast<ushort4*>(abuf + idx4) = o;
}

extern "C" void kernel_launch(void* const* d_in, const int* in_sizes, int n_in,
                              void* d_out, int out_size, void* d_ws, size_t ws_size,
                              hipStream_t stream) {
    (void)in_sizes; (void)n_in; (void)out_size; (void)d_ws; (void)ws_size;
    const float* x    = (const float*)d_in[0];
    const float* c    = (const float*)d_in[1];
    const int*   mask = (const int*)d_in[2];
    const float* ln_w = (const float*)d_in[3];
    const float* ln_b = (const float*)d_in[4];
    const float* Wq   = (const float*)d_in[5];
    const float* Wo   = (const float*)d_in[6];
    float* out  = (float*)d_out;                    // o: 1,048,576 fp32 (4 MB)
    float* out2 = out + (size_t)B_ * NX_ * D_;      // kv0: 8,388,608 fp32 (32 MB)

    // scratch layout inside out2 (float-slot offsets); kv0 runs LAST and overwrites.
    float* base = out2;
    unsigned short* qbf      = (unsigned short*)(base);               // 2 MB   [0, 524288)
    unsigned*       maskbits = (unsigned*)(base + 524288);            // 0.5 MB [524288, 655360)
    float*          part_o   = base + 655360;                         // 16 MB  [655360, 4849664)
    float*          part_l   = base + 4849664;                        // 0.25MB [4849664, 4915200)
    unsigned short* WqT      = (unsigned short*)(base + 4915200);     // 2 MB
    unsigned short* WoT      = (unsigned short*)(base + 5439488);     // 2 MB
    unsigned short* xnb      = (unsigned short*)(base + 5963776);     // 2 MB
    unsigned short* abuf     = (unsigned short*)(base + 6488064);     // 2 MB  (ends 7012352 < 8388608)

    const int M = B_ * NX_;   // 1024

    ln_kernel<<<M, 256, 0, stream>>>(x, ln_w, ln_b, xnb);
    tcast_kernel<<<dim3(16, 16), 256, 0, stream>>>(Wq, WqT);
    tcast_kernel<<<dim3(16, 16), 256, 0, stream>>>(Wo, WoT);
    pack_mask_kernel<<<(B_ * NX_ * NC_ / 32) / 256, 256, 0, stream>>>(mask, maskbits);
    gemm_bt_kernel<<<dim3(16, 16), 256, 0, stream>>>(xnb, WqT, nullptr, qbf);
    attn_kernel<<<NSPLIT * 256, 256, 0, stream>>>(qbf, c, maskbits, part_o, part_l);
    combine_kernel<<<(B_ * NX_ * D_ / 4) / 256, 256, 0, stream>>>(part_o, part_l, abuf);
    gemm_bt_kernel<<<dim3(16, 16), 256, 0, stream>>>(abuf, WoT, out, nullptr);
    kv0_kernel<<<(B_ * H_ * NC_ * HD_ / 4) / 256, 256, 0, stream>>>(c, out2);
}